// Round 2
// baseline (4805.973 us; speedup 1.0000x reference)
//
#include <hip/hip_runtime.h>
#include <stdint.h>

#define B_ 128
#define S_ 512
#define E_ 256
#define H_ 256
#define G3 768
#define C_ 345
#define TC_ 64
#define NCH (S_ / TC_)

typedef __attribute__((ext_vector_type(8))) short short8;
typedef __attribute__((ext_vector_type(4))) float f32x4;
typedef __attribute__((ext_vector_type(4))) unsigned int uint4_;

__device__ __forceinline__ unsigned short f2bf(float f) {
  union { float f; uint32_t u; } v; v.f = f;
  uint32_t r = v.u + 0x7FFF + ((v.u >> 16) & 1);
  return (unsigned short)(r >> 16);
}
__device__ __forceinline__ float bf2f(unsigned short u) {
  union { uint32_t u; float f; } v; v.u = ((uint32_t)u) << 16; return v.f;
}
__device__ __forceinline__ float sigmf(float x) { return 1.f / (1.f + __expf(-x)); }
__device__ __forceinline__ float tanhf_(float x) { return 2.f / (1.f + __expf(-2.f * x)) - 1.f; }

__device__ __forceinline__ void gload_lds16(const void* g, void* l) {
  __builtin_amdgcn_global_load_lds(
      (const __attribute__((address_space(1))) unsigned int*)g,
      (__attribute__((address_space(3))) unsigned int*)l, 16, 0, 0);
}

__global__ void k_sentinel(float* dout) { dout[0] = 1.0e6f; }

// ---------------- fp32 -> bf16 convert
__global__ __launch_bounds__(256) void k_cvt(const float* __restrict__ s,
                                             unsigned short* __restrict__ d, int n) {
  int i = blockIdx.x * blockDim.x + threadIdx.x;
  if (i < n) d[i] = f2bf(s[i]);
}

// ---------------- embed chunk (time-major out): xeF[lt][b][e] for t=s0+lt,
// xeB[lt][b][e] for t=S-1-s0-lt.
__global__ __launch_bounds__(256) void k_embed_chunk(
    const float* __restrict__ coord, const int* __restrict__ flag,
    const int* __restrict__ pos, const float* __restrict__ cW,
    const float* __restrict__ femb, unsigned short* __restrict__ xeF,
    unsigned short* __restrict__ xeB, int s0) {
  int gid = blockIdx.x * 256 + threadIdx.x;  // 2*TC*B*32 threads
  int row = gid >> 5, e0 = (gid & 31) * 8;
  int isB = row >= (TC_ * B_);
  int r = isB ? row - TC_ * B_ : row;
  int lt = r >> 7, b = r & 127;
  int t = isB ? (S_ - 1 - (s0 + lt)) : (s0 + lt);
  size_t src = (size_t)b * S_ + t;
  float c0 = coord[src * 2], c1 = coord[src * 2 + 1];
  int f = flag[src], p = pos[src];
  unsigned short* out = (isB ? xeB : xeF) + (size_t)r * E_;
#pragma unroll
  for (int i = 0; i < 8; i++) {
    int e = e0 + i;
    float v = c0 * cW[e * 2] + c1 * cW[e * 2 + 1] + femb[f * E_ + e] + femb[p * E_ + e];
    out[e] = f2bf(v);
  }
}

// ---------------- C[M][N] = A[M][K] @ B[N][K]^T (bf16 in/out, f32 accum)
__global__ __launch_bounds__(256) void k_gemm_bt(
    const unsigned short* __restrict__ A, const unsigned short* __restrict__ Bm,
    unsigned short* __restrict__ C, int M, int N, int K) {
  __shared__ unsigned short As[128 * 32];
  __shared__ unsigned short Bs[128 * 32];
  int nt_ = N >> 7;
  int bx = blockIdx.x % nt_, by = blockIdx.x / nt_;
  int tid = threadIdx.x, lane = tid & 63, w = tid >> 6;
  int wr = (w >> 1) * 64, wc = (w & 1) * 64;
  f32x4 acc[4][4] = {};
  int lr = lane >> 2;
  int lc = (lane & 3) * 8;
  for (int kt = 0; kt < K; kt += 32) {
#pragma unroll
    for (int q = 0; q < 2; q++) {
      int r = w * 32 + q * 16;
      gload_lds16(A + (size_t)(by * 128 + r + lr) * K + kt + lc, &As[r * 32]);
      gload_lds16(Bm + (size_t)(bx * 128 + r + lr) * K + kt + lc, &Bs[r * 32]);
    }
    __syncthreads();
    short8 af[4], bf[4];
#pragma unroll
    for (int i = 0; i < 4; i++)
      af[i] = *(const short8*)&As[(wr + i * 16 + (lane & 15)) * 32 + (lane >> 4) * 8];
#pragma unroll
    for (int i = 0; i < 4; i++)
      bf[i] = *(const short8*)&Bs[(wc + i * 16 + (lane & 15)) * 32 + (lane >> 4) * 8];
#pragma unroll
    for (int i = 0; i < 4; i++)
#pragma unroll
      for (int j = 0; j < 4; j++)
        acc[i][j] = __builtin_amdgcn_mfma_f32_16x16x32_bf16(af[i], bf[j], acc[i][j], 0, 0, 0);
    __syncthreads();
  }
#pragma unroll
  for (int i = 0; i < 4; i++)
#pragma unroll
    for (int j = 0; j < 4; j++)
#pragma unroll
      for (int e = 0; e < 4; e++) {
        int rrow = by * 128 + wr + i * 16 + (lane >> 4) * 4 + e;
        int ccol = bx * 128 + wc + j * 16 + (lane & 15);
        C[(size_t)rrow * N + ccol] = f2bf(acc[i][j][e]);
      }
}

// ---------------- GRU scan chunk (TC steps), h carried in global hstate (f32).
// grid = ndir*8 blocks x 512 thr. Block = (dir, batch-block of 16).
// xpF/xpB are chunk-local time-major [TC][128][768] bf16.
__global__ __launch_bounds__(512) void k_scan_chunk(
    const unsigned short* __restrict__ xpF, const unsigned short* __restrict__ xpB,
    const unsigned short* __restrict__ Whh,  // [ndir][768][256] bf16
    const float* __restrict__ bih, const float* __restrict__ bhh,
    float* __restrict__ hstate,          // [ndir][128][256] f32
    unsigned short* __restrict__ hout,   // [S*128][512] bf16 or null
    int s0, int write_hout) {
  __shared__ __align__(16) char smem[114688];    // 64K wlds + 16K hbf + 32K hf32
  char* wlds = smem;
  char* hbf = smem + 65536;
  float* hf32 = (float*)(smem + 65536 + 16384);

  int tid = threadIdx.x, lane = tid & 63, w = tid >> 6;
  int dir = blockIdx.x >> 3;
  int b0 = (blockIdx.x & 7) * 16;

  const unsigned short* Wd = Whh + (size_t)dir * G3 * H_;
  const unsigned short* xq = dir ? xpB : xpF;
  const float* bihd = bih + dir * G3;
  const float* bhhd = bhh + dir * G3;
  float* hst = hstate + (size_t)dir * B_ * H_;

  // init h buffers
  if (s0 == 0) {
    for (int i = tid; i < 12288; i += 512) ((uint32_t*)hbf)[i] = 0;
  } else {
    for (int i = tid; i < 4096; i += 512) {
      int br = i >> 8, j = i & 255;
      float hv = hst[(size_t)(b0 + br) * H_ + j];
      hf32[br * H_ + j] = hv;
      *(unsigned short*)(hbf + br * 512 + ((j * 2) ^ ((br & 7) << 4))) = f2bf(hv);
    }
  }

  // register-resident weight fragments: tiles t=0..4 (t = gate*2 + jt)
  short8 wreg[5][8];
#pragma unroll
  for (int t = 0; t < 5; t++) {
    int grow = (t >> 1) * H_ + 32 * w + (t & 1) * 16 + (lane & 15);
#pragma unroll
    for (int kt = 0; kt < 8; kt++)
      wreg[t][kt] = *(const short8*)&Wd[(size_t)grow * H_ + kt * 32 + (lane >> 4) * 8];
  }
  // LDS tile: n-gate, jt=1 (rows 512+32w+16..+31), swizzled
  {
    int base_row = 2 * H_ + 32 * w + 16;
    char* wt = wlds + w * 8192;
    for (int it = 0; it < 8; it++) {
      int r = it * 2 + (lane >> 5);
      int cb = (lane & 31) * 16;
      uint4_ v = *(const uint4_*)&Wd[(size_t)(base_row + r) * H_ + cb / 2];
      *(uint4_*)(wt + r * 512 + (cb ^ ((r & 7) << 4))) = v;
    }
  }
  float brih[2][3], brhh[2][3];
#pragma unroll
  for (int jt = 0; jt < 2; jt++)
#pragma unroll
    for (int g = 0; g < 3; g++) {
      int gg = g * H_ + 32 * w + jt * 16 + (lane & 15);
      brih[jt][g] = bihd[gg];
      brhh[jt][g] = bhhd[gg];
    }
  __syncthreads();

  int p = 0;
  for (int sl = 0; sl < TC_; sl++) {
    int t = dir ? (S_ - 1 - (s0 + sl)) : (s0 + sl);
    f32x4 acc[6] = {};
    char* hb = hbf + p * 8192;
#pragma unroll
    for (int kt = 0; kt < 8; kt++) {
      int ar = lane & 15;
      short8 af = *(const short8*)(hb + ar * 512 + ((kt * 64 + (lane >> 4) * 16) ^ ((ar & 7) << 4)));
#pragma unroll
      for (int t5 = 0; t5 < 5; t5++)
        acc[t5] = __builtin_amdgcn_mfma_f32_16x16x32_bf16(af, wreg[t5][kt], acc[t5], 0, 0, 0);
      short8 bf = *(const short8*)(wlds + w * 8192 + ar * 512 +
                                   ((kt * 64 + (lane >> 4) * 16) ^ ((ar & 7) << 4)));
      acc[5] = __builtin_amdgcn_mfma_f32_16x16x32_bf16(af, bf, acc[5], 0, 0, 0);
    }
    char* hbn = hbf + (p ^ 1) * 8192;
    float* hfp = hf32 + p * 4096;
    float* hfn = hf32 + (p ^ 1) * 4096;
#pragma unroll
    for (int jt = 0; jt < 2; jt++) {
      int j = 32 * w + jt * 16 + (lane & 15);
#pragma unroll
      for (int e = 0; e < 4; e++) {
        int br = (lane >> 4) * 4 + e;
        size_t xbase = ((size_t)sl * B_ + (b0 + br)) * G3;
        float xr = bf2f(xq[xbase + j]) + brih[jt][0];
        float xz = bf2f(xq[xbase + H_ + j]) + brih[jt][1];
        float xn = bf2f(xq[xbase + 2 * H_ + j]) + brih[jt][2];
        float gr = acc[0 + jt][e] + brhh[jt][0];
        float gz = acc[2 + jt][e] + brhh[jt][1];
        float gn = acc[4 + jt][e] + brhh[jt][2];
        float r = sigmf(xr + gr);
        float z = sigmf(xz + gz);
        float n = tanhf_(xn + r * gn);
        float hp = hfp[br * H_ + j];
        float hv = (1.f - z) * n + z * hp;
        hfn[br * H_ + j] = hv;
        unsigned short hb16 = f2bf(hv);
        *(unsigned short*)(hbn + br * 512 + ((j * 2) ^ ((br & 7) << 4))) = hb16;
        if (write_hout)
          hout[((size_t)t * B_ + (b0 + br)) * 512 + dir * H_ + j] = hb16;
      }
    }
    __syncthreads();
    p ^= 1;
  }
  // p back to 0 (TC even); store carry
  {
    float* hfp = hf32 + p * 4096;
    for (int i = tid; i < 4096; i += 512)
      hst[(size_t)(b0 + (i >> 8)) * H_ + (i & 255)] = hfp[i];
  }
}

// ---------------- layer-2 bwd single step + featur + logits
__global__ __launch_bounds__(256) void k_final(
    const unsigned short* __restrict__ h1, const float* __restrict__ hlastf,
    const float* __restrict__ Wih1, const float* __restrict__ bih1,
    const float* __restrict__ bhh1, const float* __restrict__ outW,
    const float* __restrict__ outb, float* __restrict__ dout) {
  typedef __attribute__((ext_vector_type(4))) float f4;
  int b = blockIdx.x, tid = threadIdx.x;
  __shared__ float xt[512];
  __shared__ float feat[512];
  for (int i = tid; i < 512; i += 256)
    xt[i] = bf2f(h1[((size_t)(S_ - 1) * B_ + b) * 512 + i]);
  __syncthreads();
  {
    const float* w0 = Wih1 + (size_t)G3 * 512;  // bwd direction
    f4 dr = {0.f, 0.f, 0.f, 0.f}, dz = dr, dn = dr;
    const f4* xv = (const f4*)xt;
    const f4* wr_ = (const f4*)(w0 + (size_t)tid * 512);
    const f4* wz_ = (const f4*)(w0 + (size_t)(H_ + tid) * 512);
    const f4* wn_ = (const f4*)(w0 + (size_t)(2 * H_ + tid) * 512);
    for (int k = 0; k < 128; k++) {
      f4 x = xv[k];
      dr += x * wr_[k]; dz += x * wz_[k]; dn += x * wn_[k];
    }
    float sr = dr[0] + dr[1] + dr[2] + dr[3] + bih1[G3 + tid] + bhh1[G3 + tid];
    float sz = dz[0] + dz[1] + dz[2] + dz[3] + bih1[G3 + H_ + tid] + bhh1[G3 + H_ + tid];
    float sn = dn[0] + dn[1] + dn[2] + dn[3] + bih1[G3 + 2 * H_ + tid];
    float r = sigmf(sr);
    float z = sigmf(sz);
    float n = tanhf_(sn + r * bhh1[G3 + 2 * H_ + tid]);
    feat[H_ + tid] = (1.f - z) * n;            // bwd half (h0 = 0)
    feat[tid] = hlastf[(size_t)b * H_ + tid];  // fwd half
  }
  __syncthreads();
  for (int c = tid; c < C_; c += 256) {
    const f4* wv = (const f4*)(outW + (size_t)c * 512);
    const f4* fv = (const f4*)feat;
    f4 a = {0.f, 0.f, 0.f, 0.f};
    for (int k = 0; k < 128; k++) a += fv[k] * wv[k];
    dout[(size_t)b * C_ + c] = a[0] + a[1] + a[2] + a[3] + outb[c];
  }
  float* fout = dout + (size_t)B_ * C_;
  for (int i = tid; i < 512; i += 256) fout[(size_t)b * 512 + i] = feat[i];
}

extern "C" void kernel_launch(void* const* d_in, const int* in_sizes, int n_in,
                              void* d_out, int out_size, void* d_ws, size_t ws_size,
                              hipStream_t stream) {
  const float* coord = (const float*)d_in[0];
  const int* flag = (const int*)d_in[1];
  const int* pos = (const int*)d_in[2];
  const float* cW = (const float*)d_in[3];
  const float* femb = (const float*)d_in[4];
  const float* Wih0 = (const float*)d_in[5];
  const float* Whh0 = (const float*)d_in[6];
  const float* bih0 = (const float*)d_in[7];
  const float* bhh0 = (const float*)d_in[8];
  const float* Wih1 = (const float*)d_in[9];
  const float* Whh1 = (const float*)d_in[10];
  const float* bih1 = (const float*)d_in[11];
  const float* bhh1 = (const float*)d_in[12];
  const float* outW = (const float*)d_in[13];
  const float* outb = (const float*)d_in[14];
  float* dout = (float*)d_out;

  char* ws = (char*)d_ws;
  size_t off = 0;
  unsigned short* W0b   = (unsigned short*)(ws + off); off += (size_t)2 * G3 * E_ * 2;   // 786432
  unsigned short* Whh0b = (unsigned short*)(ws + off); off += (size_t)2 * G3 * H_ * 2;   // 786432
  unsigned short* W1b   = (unsigned short*)(ws + off); off += (size_t)G3 * 512 * 2;      // 786432
  unsigned short* Whh1b = (unsigned short*)(ws + off); off += (size_t)G3 * H_ * 2;       // 393216
  float* hstate0        = (float*)(ws + off);          off += (size_t)2 * B_ * H_ * 4;   // 262144
  float* hstate1        = (float*)(ws + off);          off += (size_t)B_ * H_ * 4;       // 131072
  unsigned short* xeF   = (unsigned short*)(ws + off); off += (size_t)TC_ * B_ * E_ * 2; // 4 MB
  unsigned short* xeB   = (unsigned short*)(ws + off); off += (size_t)TC_ * B_ * E_ * 2; // 4 MB
  unsigned short* xpF   = (unsigned short*)(ws + off); off += (size_t)TC_ * B_ * G3 * 2; // 12 MB
  unsigned short* xpB   = (unsigned short*)(ws + off); off += (size_t)TC_ * B_ * G3 * 2; // 12 MB
  unsigned short* h1    = (unsigned short*)(ws + off); off += (size_t)S_ * B_ * 512 * 2; // 64 MB

  if (ws_size < off) {  // workspace too small: emit sentinel and bail
    k_sentinel<<<1, 1, 0, stream>>>(dout);
    return;
  }

  k_cvt<<<(2 * G3 * E_ + 255) / 256, 256, 0, stream>>>(Wih0, W0b, 2 * G3 * E_);
  k_cvt<<<(2 * G3 * H_ + 255) / 256, 256, 0, stream>>>(Whh0, Whh0b, 2 * G3 * H_);
  k_cvt<<<(G3 * 512 + 255) / 256, 256, 0, stream>>>(Wih1, W1b, G3 * 512);   // fwd dir only
  k_cvt<<<(G3 * H_ + 255) / 256, 256, 0, stream>>>(Whh1, Whh1b, G3 * H_);   // fwd dir only

  const int MCH = TC_ * B_;  // 8192 rows per chunk GEMM
  for (int c = 0; c < NCH; c++) {
    int s0 = c * TC_;
    k_embed_chunk<<<(2 * MCH * 32) / 256, 256, 0, stream>>>(coord, flag, pos, cW, femb,
                                                            xeF, xeB, s0);
    k_gemm_bt<<<(G3 / 128) * (MCH / 128), 256, 0, stream>>>(xeF, W0b, xpF, MCH, G3, E_);
    k_gemm_bt<<<(G3 / 128) * (MCH / 128), 256, 0, stream>>>(xeB, W0b + (size_t)G3 * E_,
                                                            xpB, MCH, G3, E_);
    k_scan_chunk<<<16, 512, 0, stream>>>(xpF, xpB, Whh0b, bih0, bhh0, hstate0, h1, s0, 1);
  }
  for (int c = 0; c < NCH; c++) {
    int s0 = c * TC_;
    k_gemm_bt<<<(G3 / 128) * (MCH / 128), 256, 0, stream>>>(
        h1 + (size_t)s0 * B_ * 512, W1b, xpF, MCH, G3, 512);
    k_scan_chunk<<<8, 512, 0, stream>>>(xpF, xpF, Whh1b, bih1, bhh1, hstate1, nullptr, s0, 0);
  }
  k_final<<<B_, 256, 0, stream>>>(h1, hstate1, Wih1, bih1, bhh1, outW, outb, dout);
}

// Round 3
// 4269.175 us; speedup vs baseline: 1.1257x; 1.1257x over previous
//
#include <hip/hip_runtime.h>
#include <stdint.h>

#define B_ 128
#define S_ 512
#define E_ 256
#define H_ 256
#define G3 768
#define C_ 345
#define TC_ 64
#define NCH (S_ / TC_)

typedef __attribute__((ext_vector_type(8))) short short8;
typedef __attribute__((ext_vector_type(4))) float f32x4;
typedef __attribute__((ext_vector_type(4))) unsigned int uint4_;

__device__ __forceinline__ unsigned short f2bf(float f) {
  union { float f; uint32_t u; } v; v.f = f;
  uint32_t r = v.u + 0x7FFF + ((v.u >> 16) & 1);
  return (unsigned short)(r >> 16);
}
__device__ __forceinline__ float bf2f(unsigned short u) {
  union { uint32_t u; float f; } v; v.u = ((uint32_t)u) << 16; return v.f;
}
__device__ __forceinline__ float sigmf(float x) { return 1.f / (1.f + __expf(-x)); }
__device__ __forceinline__ float tanhf_(float x) { return 2.f / (1.f + __expf(-2.f * x)) - 1.f; }

__device__ __forceinline__ void gload_lds16(const void* g, void* l) {
  __builtin_amdgcn_global_load_lds(
      (const __attribute__((address_space(1))) unsigned int*)g,
      (__attribute__((address_space(3))) unsigned int*)l, 16, 0, 0);
}

__global__ void k_sentinel(float* dout) { dout[0] = 1.0e6f; }

// ---------------- fp32 -> bf16 convert
__global__ __launch_bounds__(256) void k_cvt(const float* __restrict__ s,
                                             unsigned short* __restrict__ d, int n) {
  int i = blockIdx.x * blockDim.x + threadIdx.x;
  if (i < n) d[i] = f2bf(s[i]);
}

// ---------------- embed chunk (time-major out): xeF[lt][b][e] for t=s0+lt,
// xeB[lt][b][e] for t=S-1-s0-lt.
__global__ __launch_bounds__(256) void k_embed_chunk(
    const float* __restrict__ coord, const int* __restrict__ flag,
    const int* __restrict__ pos, const float* __restrict__ cW,
    const float* __restrict__ femb, unsigned short* __restrict__ xeF,
    unsigned short* __restrict__ xeB, int s0) {
  int gid = blockIdx.x * 256 + threadIdx.x;  // 2*TC*B*32 threads
  int row = gid >> 5, e0 = (gid & 31) * 8;
  int isB = row >= (TC_ * B_);
  int r = isB ? row - TC_ * B_ : row;
  int lt = r >> 7, b = r & 127;
  int t = isB ? (S_ - 1 - (s0 + lt)) : (s0 + lt);
  size_t src = (size_t)b * S_ + t;
  float c0 = coord[src * 2], c1 = coord[src * 2 + 1];
  int f = flag[src], p = pos[src];
  unsigned short* out = (isB ? xeB : xeF) + (size_t)r * E_;
#pragma unroll
  for (int i = 0; i < 8; i++) {
    int e = e0 + i;
    float v = c0 * cW[e * 2] + c1 * cW[e * 2 + 1] + femb[f * E_ + e] + femb[p * E_ + e];
    out[e] = f2bf(v);
  }
}

// ---------------- C[M][N] = A[M][K] @ B[N][K]^T (+ optional f32 bias[col])
__global__ __launch_bounds__(256) void k_gemm_bt(
    const unsigned short* __restrict__ A, const unsigned short* __restrict__ Bm,
    unsigned short* __restrict__ C, const float* __restrict__ bias,
    int M, int N, int K) {
  __shared__ unsigned short As[128 * 32];
  __shared__ unsigned short Bs[128 * 32];
  int nt_ = N >> 7;
  int bx = blockIdx.x % nt_, by = blockIdx.x / nt_;
  int tid = threadIdx.x, lane = tid & 63, w = tid >> 6;
  int wr = (w >> 1) * 64, wc = (w & 1) * 64;
  f32x4 acc[4][4] = {};
  int lr = lane >> 2;
  int lc = (lane & 3) * 8;
  for (int kt = 0; kt < K; kt += 32) {
#pragma unroll
    for (int q = 0; q < 2; q++) {
      int r = w * 32 + q * 16;
      gload_lds16(A + (size_t)(by * 128 + r + lr) * K + kt + lc, &As[r * 32]);
      gload_lds16(Bm + (size_t)(bx * 128 + r + lr) * K + kt + lc, &Bs[r * 32]);
    }
    __syncthreads();
    short8 af[4], bf[4];
#pragma unroll
    for (int i = 0; i < 4; i++)
      af[i] = *(const short8*)&As[(wr + i * 16 + (lane & 15)) * 32 + (lane >> 4) * 8];
#pragma unroll
    for (int i = 0; i < 4; i++)
      bf[i] = *(const short8*)&Bs[(wc + i * 16 + (lane & 15)) * 32 + (lane >> 4) * 8];
#pragma unroll
    for (int i = 0; i < 4; i++)
#pragma unroll
      for (int j = 0; j < 4; j++)
        acc[i][j] = __builtin_amdgcn_mfma_f32_16x16x32_bf16(af[i], bf[j], acc[i][j], 0, 0, 0);
    __syncthreads();
  }
#pragma unroll
  for (int i = 0; i < 4; i++)
#pragma unroll
    for (int j = 0; j < 4; j++)
#pragma unroll
      for (int e = 0; e < 4; e++) {
        int rrow = by * 128 + wr + i * 16 + (lane >> 4) * 4 + e;
        int ccol = bx * 128 + wc + j * 16 + (lane & 15);
        float v = acc[i][j][e] + (bias ? bias[ccol] : 0.f);
        C[(size_t)rrow * N + ccol] = f2bf(v);
      }
}

// ---------------- GRU scan chunk (TC steps), h carried in global hstate (f32).
// grid = ndir*8 blocks x 512 thr. Block = (dir, batch-block of 16).
// xpF/xpB chunk-local time-major [TC][128][768] bf16, b_ih ALREADY folded in.
// Weights: 5/6 N-tiles in VGPRs, 1/6 in LDS; fp32 h carry in per-lane regs;
// xp prefetched one step ahead into LDS via global_load_lds.
__global__ __launch_bounds__(512, 2) void k_scan_chunk(
    const unsigned short* __restrict__ xpF, const unsigned short* __restrict__ xpB,
    const unsigned short* __restrict__ Whh,  // [ndir][768][256] bf16
    const float* __restrict__ bhh,           // [ndir][768]
    float* __restrict__ hstate,              // [ndir][128][256] f32
    unsigned short* __restrict__ hout,       // [S*128][512] bf16 or null
    int s0, int write_hout) {
  __shared__ __align__(16) char smem[131072];  // 64K wlds + 16K hbf + 48K xlds
  char* wlds = smem;
  char* hbf = smem + 65536;
  char* xlds = smem + 65536 + 16384;

  int tid = threadIdx.x, lane = tid & 63, w = tid >> 6;
  int dir = blockIdx.x >> 3;
  int b0 = (blockIdx.x & 7) * 16;

  const unsigned short* Wd = Whh + (size_t)dir * G3 * H_;
  const unsigned short* xq = dir ? xpB : xpF;
  const float* bhhd = bhh + dir * G3;
  float* hst = hstate + (size_t)dir * B_ * H_;

  float hreg[2][4];

  // init h (regs + bf16 LDS copy, buffer 0)
  if (s0 == 0) {
    for (int i = tid; i < 4096; i += 512) ((uint32_t*)hbf)[i] = 0;
#pragma unroll
    for (int jt = 0; jt < 2; jt++)
#pragma unroll
      for (int e = 0; e < 4; e++) hreg[jt][e] = 0.f;
  } else {
#pragma unroll
    for (int jt = 0; jt < 2; jt++)
#pragma unroll
      for (int e = 0; e < 4; e++) {
        int j = 32 * w + jt * 16 + (lane & 15);
        int br = (lane >> 4) * 4 + e;
        float hv = hst[(size_t)(b0 + br) * H_ + j];
        hreg[jt][e] = hv;
        *(unsigned short*)(hbf + br * 512 + ((j * 2) ^ ((br & 7) << 4))) = f2bf(hv);
      }
  }

  // stage xp for step 0 into xlds buffer 0 (3 wave-instrs per wave)
  {
    const char* gsrc = (const char*)(xq + ((size_t)0 * B_ + b0) * G3);
#pragma unroll
    for (int q = 0; q < 3; q++) {
      int o = (w * 3 + q) * 1024;
      gload_lds16(gsrc + o + lane * 16, xlds + o);
    }
  }

  // register-resident weight fragments: tiles t=0..4 (t = gate*2 + jt)
  short8 wreg[5][8];
#pragma unroll
  for (int t = 0; t < 5; t++) {
    int grow = (t >> 1) * H_ + 32 * w + (t & 1) * 16 + (lane & 15);
#pragma unroll
    for (int kt = 0; kt < 8; kt++)
      wreg[t][kt] = *(const short8*)&Wd[(size_t)grow * H_ + kt * 32 + (lane >> 4) * 8];
  }
  // LDS tile: n-gate, jt=1 (rows 512+32w+16..+31), swizzled
  {
    int base_row = 2 * H_ + 32 * w + 16;
    char* wt = wlds + w * 8192;
    for (int it = 0; it < 8; it++) {
      int r = it * 2 + (lane >> 5);
      int cb = (lane & 31) * 16;
      uint4_ v = *(const uint4_*)&Wd[(size_t)(base_row + r) * H_ + cb / 2];
      *(uint4_*)(wt + r * 512 + (cb ^ ((r & 7) << 4))) = v;
    }
  }
  float brhh[2][3];
#pragma unroll
  for (int jt = 0; jt < 2; jt++)
#pragma unroll
    for (int g = 0; g < 3; g++)
      brhh[jt][g] = bhhd[g * H_ + 32 * w + jt * 16 + (lane & 15)];
  __syncthreads();

  int p = 0;
  for (int sl = 0; sl < TC_; sl++) {
    // prefetch xp for step sl+1 into xlds[p^1] (clamped; hidden under this step)
    {
      int sp = (sl + 1 < TC_) ? sl + 1 : sl;
      const char* gsrc = (const char*)(xq + ((size_t)sp * B_ + b0) * G3);
      char* ldst = xlds + (p ^ 1) * 24576;
#pragma unroll
      for (int q = 0; q < 3; q++) {
        int o = (w * 3 + q) * 1024;
        gload_lds16(gsrc + o + lane * 16, ldst + o);
      }
    }
    // h @ Whh^T for this wave's 6 gate-tiles
    f32x4 acc[6] = {};
    char* hb = hbf + p * 8192;
#pragma unroll
    for (int kt = 0; kt < 8; kt++) {
      int ar = lane & 15;
      short8 af = *(const short8*)(hb + ar * 512 +
                                   ((kt * 64 + (lane >> 4) * 16) ^ ((ar & 7) << 4)));
#pragma unroll
      for (int t5 = 0; t5 < 5; t5++)
        acc[t5] = __builtin_amdgcn_mfma_f32_16x16x32_bf16(af, wreg[t5][kt], acc[t5], 0, 0, 0);
      short8 bf = *(const short8*)(wlds + w * 8192 + ar * 512 +
                                   ((kt * 64 + (lane >> 4) * 16) ^ ((ar & 7) << 4)));
      acc[5] = __builtin_amdgcn_mfma_f32_16x16x32_bf16(af, bf, acc[5], 0, 0, 0);
    }
    // pointwise: lane holds D[br=(lane>>4)*4+e][j]
    int t = dir ? (S_ - 1 - (s0 + sl)) : (s0 + sl);
    char* hbn = hbf + (p ^ 1) * 8192;
    const unsigned short* xl = (const unsigned short*)(xlds + p * 24576);
#pragma unroll
    for (int jt = 0; jt < 2; jt++) {
      int j = 32 * w + jt * 16 + (lane & 15);
#pragma unroll
      for (int e = 0; e < 4; e++) {
        int br = (lane >> 4) * 4 + e;
        const unsigned short* xr_ = xl + br * G3;
        float xr = bf2f(xr_[j]);
        float xz = bf2f(xr_[H_ + j]);
        float xn = bf2f(xr_[2 * H_ + j]);
        float gr = acc[0 + jt][e] + brhh[jt][0];
        float gz = acc[2 + jt][e] + brhh[jt][1];
        float gn = acc[4 + jt][e] + brhh[jt][2];
        float r = sigmf(xr + gr);
        float z = sigmf(xz + gz);
        float n = tanhf_(xn + r * gn);
        float hv = (1.f - z) * n + z * hreg[jt][e];
        hreg[jt][e] = hv;
        unsigned short hb16 = f2bf(hv);
        *(unsigned short*)(hbn + br * 512 + ((j * 2) ^ ((br & 7) << 4))) = hb16;
        if (write_hout)
          hout[((size_t)t * B_ + (b0 + br)) * 512 + dir * H_ + j] = hb16;
      }
    }
    __syncthreads();
    p ^= 1;
  }
  // store carry
#pragma unroll
  for (int jt = 0; jt < 2; jt++)
#pragma unroll
    for (int e = 0; e < 4; e++) {
      int j = 32 * w + jt * 16 + (lane & 15);
      int br = (lane >> 4) * 4 + e;
      hst[(size_t)(b0 + br) * H_ + j] = hreg[jt][e];
    }
}

// ---------------- layer-2 bwd single step + featur + logits
__global__ __launch_bounds__(256) void k_final(
    const unsigned short* __restrict__ h1, const float* __restrict__ hlastf,
    const float* __restrict__ Wih1, const float* __restrict__ bih1,
    const float* __restrict__ bhh1, const float* __restrict__ outW,
    const float* __restrict__ outb, float* __restrict__ dout) {
  typedef __attribute__((ext_vector_type(4))) float f4;
  int b = blockIdx.x, tid = threadIdx.x;
  __shared__ float xt[512];
  __shared__ float feat[512];
  for (int i = tid; i < 512; i += 256)
    xt[i] = bf2f(h1[((size_t)(S_ - 1) * B_ + b) * 512 + i]);
  __syncthreads();
  {
    const float* w0 = Wih1 + (size_t)G3 * 512;  // bwd direction
    f4 dr = {0.f, 0.f, 0.f, 0.f}, dz = dr, dn = dr;
    const f4* xv = (const f4*)xt;
    const f4* wr_ = (const f4*)(w0 + (size_t)tid * 512);
    const f4* wz_ = (const f4*)(w0 + (size_t)(H_ + tid) * 512);
    const f4* wn_ = (const f4*)(w0 + (size_t)(2 * H_ + tid) * 512);
    for (int k = 0; k < 128; k++) {
      f4 x = xv[k];
      dr += x * wr_[k]; dz += x * wz_[k]; dn += x * wn_[k];
    }
    float sr = dr[0] + dr[1] + dr[2] + dr[3] + bih1[G3 + tid] + bhh1[G3 + tid];
    float sz = dz[0] + dz[1] + dz[2] + dz[3] + bih1[G3 + H_ + tid] + bhh1[G3 + H_ + tid];
    float sn = dn[0] + dn[1] + dn[2] + dn[3] + bih1[G3 + 2 * H_ + tid];
    float r = sigmf(sr);
    float z = sigmf(sz);
    float n = tanhf_(sn + r * bhh1[G3 + 2 * H_ + tid]);
    feat[H_ + tid] = (1.f - z) * n;            // bwd half (h0 = 0)
    feat[tid] = hlastf[(size_t)b * H_ + tid];  // fwd half
  }
  __syncthreads();
  for (int c = tid; c < C_; c += 256) {
    const f4* wv = (const f4*)(outW + (size_t)c * 512);
    const f4* fv = (const f4*)feat;
    f4 a = {0.f, 0.f, 0.f, 0.f};
    for (int k = 0; k < 128; k++) a += fv[k] * wv[k];
    dout[(size_t)b * C_ + c] = a[0] + a[1] + a[2] + a[3] + outb[c];
  }
  float* fout = dout + (size_t)B_ * C_;
  for (int i = tid; i < 512; i += 256) fout[(size_t)b * 512 + i] = feat[i];
}

extern "C" void kernel_launch(void* const* d_in, const int* in_sizes, int n_in,
                              void* d_out, int out_size, void* d_ws, size_t ws_size,
                              hipStream_t stream) {
  const float* coord = (const float*)d_in[0];
  const int* flag = (const int*)d_in[1];
  const int* pos = (const int*)d_in[2];
  const float* cW = (const float*)d_in[3];
  const float* femb = (const float*)d_in[4];
  const float* Wih0 = (const float*)d_in[5];
  const float* Whh0 = (const float*)d_in[6];
  const float* bih0 = (const float*)d_in[7];
  const float* bhh0 = (const float*)d_in[8];
  const float* Wih1 = (const float*)d_in[9];
  const float* Whh1 = (const float*)d_in[10];
  const float* bih1 = (const float*)d_in[11];
  const float* bhh1 = (const float*)d_in[12];
  const float* outW = (const float*)d_in[13];
  const float* outb = (const float*)d_in[14];
  float* dout = (float*)d_out;

  char* ws = (char*)d_ws;
  size_t off = 0;
  unsigned short* W0b   = (unsigned short*)(ws + off); off += (size_t)2 * G3 * E_ * 2;
  unsigned short* Whh0b = (unsigned short*)(ws + off); off += (size_t)2 * G3 * H_ * 2;
  unsigned short* W1b   = (unsigned short*)(ws + off); off += (size_t)G3 * 512 * 2;
  unsigned short* Whh1b = (unsigned short*)(ws + off); off += (size_t)G3 * H_ * 2;
  float* hstate0        = (float*)(ws + off);          off += (size_t)2 * B_ * H_ * 4;
  float* hstate1        = (float*)(ws + off);          off += (size_t)B_ * H_ * 4;
  unsigned short* xeF   = (unsigned short*)(ws + off); off += (size_t)TC_ * B_ * E_ * 2;
  unsigned short* xeB   = (unsigned short*)(ws + off); off += (size_t)TC_ * B_ * E_ * 2;
  unsigned short* xpF   = (unsigned short*)(ws + off); off += (size_t)TC_ * B_ * G3 * 2;
  unsigned short* xpB   = (unsigned short*)(ws + off); off += (size_t)TC_ * B_ * G3 * 2;
  unsigned short* h1    = (unsigned short*)(ws + off); off += (size_t)S_ * B_ * 512 * 2;

  if (ws_size < off) {  // workspace too small: emit sentinel and bail
    k_sentinel<<<1, 1, 0, stream>>>(dout);
    return;
  }

  k_cvt<<<(2 * G3 * E_ + 255) / 256, 256, 0, stream>>>(Wih0, W0b, 2 * G3 * E_);
  k_cvt<<<(2 * G3 * H_ + 255) / 256, 256, 0, stream>>>(Whh0, Whh0b, 2 * G3 * H_);
  k_cvt<<<(G3 * 512 + 255) / 256, 256, 0, stream>>>(Wih1, W1b, G3 * 512);   // fwd dir only
  k_cvt<<<(G3 * H_ + 255) / 256, 256, 0, stream>>>(Whh1, Whh1b, G3 * H_);   // fwd dir only

  const int MCH = TC_ * B_;  // 8192 rows per chunk GEMM
  for (int c = 0; c < NCH; c++) {
    int s0 = c * TC_;
    k_embed_chunk<<<(2 * MCH * 32) / 256, 256, 0, stream>>>(coord, flag, pos, cW, femb,
                                                            xeF, xeB, s0);
    k_gemm_bt<<<(G3 / 128) * (MCH / 128), 256, 0, stream>>>(xeF, W0b, xpF, bih0,
                                                            MCH, G3, E_);
    k_gemm_bt<<<(G3 / 128) * (MCH / 128), 256, 0, stream>>>(xeB, W0b + (size_t)G3 * E_,
                                                            xpB, bih0 + G3, MCH, G3, E_);
    k_scan_chunk<<<16, 512, 0, stream>>>(xpF, xpB, Whh0b, bhh0, hstate0, h1, s0, 1);
  }
  for (int c = 0; c < NCH; c++) {
    int s0 = c * TC_;
    k_gemm_bt<<<(G3 / 128) * (MCH / 128), 256, 0, stream>>>(
        h1 + (size_t)s0 * B_ * 512, W1b, xpF, bih1, MCH, G3, 512);
    k_scan_chunk<<<8, 512, 0, stream>>>(xpF, xpF, Whh1b, bhh1, hstate1, nullptr, s0, 0);
  }
  k_final<<<B_, 256, 0, stream>>>(h1, hstate1, Wih1, bih1, bhh1, outW, outb, dout);
}

// Round 4
// 4050.177 us; speedup vs baseline: 1.1866x; 1.0541x over previous
//
#include <hip/hip_runtime.h>
#include <stdint.h>

#define B_ 128
#define S_ 512
#define E_ 256
#define H_ 256
#define G3 768
#define C_ 345
#define TC_ 64
#define NCH (S_ / TC_)

typedef __attribute__((ext_vector_type(8))) short short8;
typedef __attribute__((ext_vector_type(4))) float f32x4;
typedef __attribute__((ext_vector_type(4))) unsigned int uint4_;

__device__ __forceinline__ unsigned short f2bf(float f) {
  union { float f; uint32_t u; } v; v.f = f;
  uint32_t r = v.u + 0x7FFF + ((v.u >> 16) & 1);
  return (unsigned short)(r >> 16);
}
__device__ __forceinline__ float bf2f(unsigned short u) {
  union { uint32_t u; float f; } v; v.u = ((uint32_t)u) << 16; return v.f;
}
__device__ __forceinline__ float sigmf(float x) { return 1.f / (1.f + __expf(-x)); }
__device__ __forceinline__ float tanhf_(float x) { return 2.f / (1.f + __expf(-2.f * x)) - 1.f; }

__device__ __forceinline__ void gload_lds16(const void* g, void* l) {
  __builtin_amdgcn_global_load_lds(
      (const __attribute__((address_space(1))) unsigned int*)g,
      (__attribute__((address_space(3))) unsigned int*)l, 16, 0, 0);
}

__global__ void k_sentinel(float* dout) { dout[0] = 1.0e6f; }

// ---------------- fp32 -> bf16 convert
__global__ __launch_bounds__(256) void k_cvt(const float* __restrict__ s,
                                             unsigned short* __restrict__ d, int n) {
  int i = blockIdx.x * blockDim.x + threadIdx.x;
  if (i < n) d[i] = f2bf(s[i]);
}

// ---------------- embed chunk (time-major out): xeF[lt][b][e] for t=s0+lt,
// xeB[lt][b][e] for t=S-1-s0-lt.
__global__ __launch_bounds__(256) void k_embed_chunk(
    const float* __restrict__ coord, const int* __restrict__ flag,
    const int* __restrict__ pos, const float* __restrict__ cW,
    const float* __restrict__ femb, unsigned short* __restrict__ xeF,
    unsigned short* __restrict__ xeB, int s0) {
  int gid = blockIdx.x * 256 + threadIdx.x;  // 2*TC*B*32 threads
  int row = gid >> 5, e0 = (gid & 31) * 8;
  int isB = row >= (TC_ * B_);
  int r = isB ? row - TC_ * B_ : row;
  int lt = r >> 7, b = r & 127;
  int t = isB ? (S_ - 1 - (s0 + lt)) : (s0 + lt);
  size_t src = (size_t)b * S_ + t;
  float c0 = coord[src * 2], c1 = coord[src * 2 + 1];
  int f = flag[src], p = pos[src];
  unsigned short* out = (isB ? xeB : xeF) + (size_t)r * E_;
#pragma unroll
  for (int i = 0; i < 8; i++) {
    int e = e0 + i;
    float v = c0 * cW[e * 2] + c1 * cW[e * 2 + 1] + femb[f * E_ + e] + femb[p * E_ + e];
    out[e] = f2bf(v);
  }
}

// ---------------- C[M][N] = A[M][K] @ B[N][K]^T (+ optional f32 bias[col])
__global__ __launch_bounds__(256) void k_gemm_bt(
    const unsigned short* __restrict__ A, const unsigned short* __restrict__ Bm,
    unsigned short* __restrict__ C, const float* __restrict__ bias,
    int M, int N, int K) {
  __shared__ unsigned short As[128 * 32];
  __shared__ unsigned short Bs[128 * 32];
  int nt_ = N >> 7;
  int bx = blockIdx.x % nt_, by = blockIdx.x / nt_;
  int tid = threadIdx.x, lane = tid & 63, w = tid >> 6;
  int wr = (w >> 1) * 64, wc = (w & 1) * 64;
  f32x4 acc[4][4] = {};
  int lr = lane >> 2;
  int lc = (lane & 3) * 8;
  for (int kt = 0; kt < K; kt += 32) {
#pragma unroll
    for (int q = 0; q < 2; q++) {
      int r = w * 32 + q * 16;
      gload_lds16(A + (size_t)(by * 128 + r + lr) * K + kt + lc, &As[r * 32]);
      gload_lds16(Bm + (size_t)(bx * 128 + r + lr) * K + kt + lc, &Bs[r * 32]);
    }
    __syncthreads();
    short8 af[4], bf[4];
#pragma unroll
    for (int i = 0; i < 4; i++)
      af[i] = *(const short8*)&As[(wr + i * 16 + (lane & 15)) * 32 + (lane >> 4) * 8];
#pragma unroll
    for (int i = 0; i < 4; i++)
      bf[i] = *(const short8*)&Bs[(wc + i * 16 + (lane & 15)) * 32 + (lane >> 4) * 8];
#pragma unroll
    for (int i = 0; i < 4; i++)
#pragma unroll
      for (int j = 0; j < 4; j++)
        acc[i][j] = __builtin_amdgcn_mfma_f32_16x16x32_bf16(af[i], bf[j], acc[i][j], 0, 0, 0);
    __syncthreads();
  }
#pragma unroll
  for (int i = 0; i < 4; i++)
#pragma unroll
    for (int j = 0; j < 4; j++)
#pragma unroll
      for (int e = 0; e < 4; e++) {
        int rrow = by * 128 + wr + i * 16 + (lane >> 4) * 4 + e;
        int ccol = bx * 128 + wc + j * 16 + (lane & 15);
        float v = acc[i][j][e] + (bias ? bias[ccol] : 0.f);
        C[(size_t)rrow * N + ccol] = f2bf(v);
      }
}

// ---------------- GRU scan chunk (TC steps), h carried in global hstate (f32).
// grid = ndir*8 blocks x 512 thr. Block = (dir, batch-block of 16).
// xpF/xpB chunk-local time-major [TC][128][768] bf16, b_ih ALREADY folded in.
// Weights: 5/6 N-tiles pinned in VGPRs (amdgpu_waves_per_eu(2,2) -> 256-VGPR
// budget; asm keep-alive kills rematerialization), 1/6 in LDS; fp32 h carry in
// per-lane regs; xp prefetched one step ahead into LDS via global_load_lds.
__global__ __launch_bounds__(512)
__attribute__((amdgpu_waves_per_eu(2, 2)))
void k_scan_chunk(
    const unsigned short* __restrict__ xpF, const unsigned short* __restrict__ xpB,
    const unsigned short* __restrict__ Whh,  // [ndir][768][256] bf16
    const float* __restrict__ bhh,           // [ndir][768]
    float* __restrict__ hstate,              // [ndir][128][256] f32
    unsigned short* __restrict__ hout,       // [S*128][512] bf16 or null
    int s0, int write_hout) {
  __shared__ __align__(16) char smem[131072];  // 64K wlds + 16K hbf + 48K xlds
  char* wlds = smem;
  char* hbf = smem + 65536;
  char* xlds = smem + 65536 + 16384;

  int tid = threadIdx.x, lane = tid & 63, w = tid >> 6;
  int dir = blockIdx.x >> 3;
  int b0 = (blockIdx.x & 7) * 16;

  const unsigned short* Wd = Whh + (size_t)dir * G3 * H_;
  const unsigned short* xq = dir ? xpB : xpF;
  const float* bhhd = bhh + dir * G3;
  float* hst = hstate + (size_t)dir * B_ * H_;

  float hreg[2][4];

  // init h (regs + bf16 LDS copy, buffer 0)
  if (s0 == 0) {
    for (int i = tid; i < 4096; i += 512) ((uint32_t*)hbf)[i] = 0;
#pragma unroll
    for (int jt = 0; jt < 2; jt++)
#pragma unroll
      for (int e = 0; e < 4; e++) hreg[jt][e] = 0.f;
  } else {
#pragma unroll
    for (int jt = 0; jt < 2; jt++)
#pragma unroll
      for (int e = 0; e < 4; e++) {
        int j = 32 * w + jt * 16 + (lane & 15);
        int br = (lane >> 4) * 4 + e;
        float hv = hst[(size_t)(b0 + br) * H_ + j];
        hreg[jt][e] = hv;
        *(unsigned short*)(hbf + br * 512 + ((j * 2) ^ ((br & 7) << 4))) = f2bf(hv);
      }
  }

  // stage xp for step 0 into xlds buffer 0 (3 wave-instrs per wave)
  {
    const char* gsrc = (const char*)(xq + ((size_t)0 * B_ + b0) * G3);
#pragma unroll
    for (int q = 0; q < 3; q++) {
      int o = (w * 3 + q) * 1024;
      gload_lds16(gsrc + o + lane * 16, xlds + o);
    }
  }

  // register-resident weight fragments: tiles t=0..4 (t = gate*2 + jt)
  short8 wreg[5][8];
#pragma unroll
  for (int t = 0; t < 5; t++) {
    int grow = (t >> 1) * H_ + 32 * w + (t & 1) * 16 + (lane & 15);
#pragma unroll
    for (int kt = 0; kt < 8; kt++)
      wreg[t][kt] = *(const short8*)&Wd[(size_t)grow * H_ + kt * 32 + (lane >> 4) * 8];
  }
  // pin: make values asm-produced so they cannot be rematerialized into the loop
#pragma unroll
  for (int t = 0; t < 5; t++)
#pragma unroll
    for (int kt = 0; kt < 8; kt++)
      asm volatile("" : "+v"(wreg[t][kt]));

  // LDS tile: n-gate, jt=1 (rows 512+32w+16..+31), swizzled
  {
    int base_row = 2 * H_ + 32 * w + 16;
    char* wt = wlds + w * 8192;
    for (int it = 0; it < 8; it++) {
      int r = it * 2 + (lane >> 5);
      int cb = (lane & 31) * 16;
      uint4_ v = *(const uint4_*)&Wd[(size_t)(base_row + r) * H_ + cb / 2];
      *(uint4_*)(wt + r * 512 + (cb ^ ((r & 7) << 4))) = v;
    }
  }
  float brhh[2][3];
#pragma unroll
  for (int jt = 0; jt < 2; jt++)
#pragma unroll
    for (int g = 0; g < 3; g++)
      brhh[jt][g] = bhhd[g * H_ + 32 * w + jt * 16 + (lane & 15)];
  __syncthreads();

  int p = 0;
  for (int sl = 0; sl < TC_; sl++) {
    // prefetch xp for step sl+1 into xlds[p^1] (clamped; hidden under this step)
    {
      int sp = (sl + 1 < TC_) ? sl + 1 : sl;
      const char* gsrc = (const char*)(xq + ((size_t)sp * B_ + b0) * G3);
      char* ldst = xlds + (p ^ 1) * 24576;
#pragma unroll
      for (int q = 0; q < 3; q++) {
        int o = (w * 3 + q) * 1024;
        gload_lds16(gsrc + o + lane * 16, ldst + o);
      }
    }
    // h @ Whh^T for this wave's 6 gate-tiles
    f32x4 acc[6] = {};
    char* hb = hbf + p * 8192;
#pragma unroll
    for (int kt = 0; kt < 8; kt++) {
      int ar = lane & 15;
      short8 af = *(const short8*)(hb + ar * 512 +
                                   ((kt * 64 + (lane >> 4) * 16) ^ ((ar & 7) << 4)));
#pragma unroll
      for (int t5 = 0; t5 < 5; t5++)
        acc[t5] = __builtin_amdgcn_mfma_f32_16x16x32_bf16(af, wreg[t5][kt], acc[t5], 0, 0, 0);
      short8 bf = *(const short8*)(wlds + w * 8192 + ar * 512 +
                                   ((kt * 64 + (lane >> 4) * 16) ^ ((ar & 7) << 4)));
      acc[5] = __builtin_amdgcn_mfma_f32_16x16x32_bf16(af, bf, acc[5], 0, 0, 0);
    }
    // pointwise: lane holds D[br=(lane>>4)*4+e][j]
    int t = dir ? (S_ - 1 - (s0 + sl)) : (s0 + sl);
    char* hbn = hbf + (p ^ 1) * 8192;
    const unsigned short* xl = (const unsigned short*)(xlds + p * 24576);
#pragma unroll
    for (int jt = 0; jt < 2; jt++) {
      int j = 32 * w + jt * 16 + (lane & 15);
#pragma unroll
      for (int e = 0; e < 4; e++) {
        int br = (lane >> 4) * 4 + e;
        const unsigned short* xr_ = xl + br * G3;
        float xr = bf2f(xr_[j]);
        float xz = bf2f(xr_[H_ + j]);
        float xn = bf2f(xr_[2 * H_ + j]);
        float gr = acc[0 + jt][e] + brhh[jt][0];
        float gz = acc[2 + jt][e] + brhh[jt][1];
        float gn = acc[4 + jt][e] + brhh[jt][2];
        float r = sigmf(xr + gr);
        float z = sigmf(xz + gz);
        float n = tanhf_(xn + r * gn);
        float hv = (1.f - z) * n + z * hreg[jt][e];
        hreg[jt][e] = hv;
        unsigned short hb16 = f2bf(hv);
        *(unsigned short*)(hbn + br * 512 + ((j * 2) ^ ((br & 7) << 4))) = hb16;
        if (write_hout)
          hout[((size_t)t * B_ + (b0 + br)) * 512 + dir * H_ + j] = hb16;
      }
    }
    __syncthreads();
    p ^= 1;
  }
  // store carry
#pragma unroll
  for (int jt = 0; jt < 2; jt++)
#pragma unroll
    for (int e = 0; e < 4; e++) {
      int j = 32 * w + jt * 16 + (lane & 15);
      int br = (lane >> 4) * 4 + e;
      hst[(size_t)(b0 + br) * H_ + j] = hreg[jt][e];
    }
}

// ---------------- layer-2 bwd single step + featur + logits
__global__ __launch_bounds__(256) void k_final(
    const unsigned short* __restrict__ h1, const float* __restrict__ hlastf,
    const float* __restrict__ Wih1, const float* __restrict__ bih1,
    const float* __restrict__ bhh1, const float* __restrict__ outW,
    const float* __restrict__ outb, float* __restrict__ dout) {
  typedef __attribute__((ext_vector_type(4))) float f4;
  int b = blockIdx.x, tid = threadIdx.x;
  __shared__ float xt[512];
  __shared__ float feat[512];
  for (int i = tid; i < 512; i += 256)
    xt[i] = bf2f(h1[((size_t)(S_ - 1) * B_ + b) * 512 + i]);
  __syncthreads();
  {
    const float* w0 = Wih1 + (size_t)G3 * 512;  // bwd direction
    f4 dr = {0.f, 0.f, 0.f, 0.f}, dz = dr, dn = dr;
    const f4* xv = (const f4*)xt;
    const f4* wr_ = (const f4*)(w0 + (size_t)tid * 512);
    const f4* wz_ = (const f4*)(w0 + (size_t)(H_ + tid) * 512);
    const f4* wn_ = (const f4*)(w0 + (size_t)(2 * H_ + tid) * 512);
    for (int k = 0; k < 128; k++) {
      f4 x = xv[k];
      dr += x * wr_[k]; dz += x * wz_[k]; dn += x * wn_[k];
    }
    float sr = dr[0] + dr[1] + dr[2] + dr[3] + bih1[G3 + tid] + bhh1[G3 + tid];
    float sz = dz[0] + dz[1] + dz[2] + dz[3] + bih1[G3 + H_ + tid] + bhh1[G3 + H_ + tid];
    float sn = dn[0] + dn[1] + dn[2] + dn[3] + bih1[G3 + 2 * H_ + tid];
    float r = sigmf(sr);
    float z = sigmf(sz);
    float n = tanhf_(sn + r * bhh1[G3 + 2 * H_ + tid]);
    feat[H_ + tid] = (1.f - z) * n;            // bwd half (h0 = 0)
    feat[tid] = hlastf[(size_t)b * H_ + tid];  // fwd half
  }
  __syncthreads();
  for (int c = tid; c < C_; c += 256) {
    const f4* wv = (const f4*)(outW + (size_t)c * 512);
    const f4* fv = (const f4*)feat;
    f4 a = {0.f, 0.f, 0.f, 0.f};
    for (int k = 0; k < 128; k++) a += fv[k] * wv[k];
    dout[(size_t)b * C_ + c] = a[0] + a[1] + a[2] + a[3] + outb[c];
  }
  float* fout = dout + (size_t)B_ * C_;
  for (int i = tid; i < 512; i += 256) fout[(size_t)b * 512 + i] = feat[i];
}

extern "C" void kernel_launch(void* const* d_in, const int* in_sizes, int n_in,
                              void* d_out, int out_size, void* d_ws, size_t ws_size,
                              hipStream_t stream) {
  const float* coord = (const float*)d_in[0];
  const int* flag = (const int*)d_in[1];
  const int* pos = (const int*)d_in[2];
  const float* cW = (const float*)d_in[3];
  const float* femb = (const float*)d_in[4];
  const float* Wih0 = (const float*)d_in[5];
  const float* Whh0 = (const float*)d_in[6];
  const float* bih0 = (const float*)d_in[7];
  const float* bhh0 = (const float*)d_in[8];
  const float* Wih1 = (const float*)d_in[9];
  const float* Whh1 = (const float*)d_in[10];
  const float* bih1 = (const float*)d_in[11];
  const float* bhh1 = (const float*)d_in[12];
  const float* outW = (const float*)d_in[13];
  const float* outb = (const float*)d_in[14];
  float* dout = (float*)d_out;

  char* ws = (char*)d_ws;
  size_t off = 0;
  unsigned short* W0b   = (unsigned short*)(ws + off); off += (size_t)2 * G3 * E_ * 2;
  unsigned short* Whh0b = (unsigned short*)(ws + off); off += (size_t)2 * G3 * H_ * 2;
  unsigned short* W1b   = (unsigned short*)(ws + off); off += (size_t)G3 * 512 * 2;
  unsigned short* Whh1b = (unsigned short*)(ws + off); off += (size_t)G3 * H_ * 2;
  float* hstate0        = (float*)(ws + off);          off += (size_t)2 * B_ * H_ * 4;
  float* hstate1        = (float*)(ws + off);          off += (size_t)B_ * H_ * 4;
  unsigned short* xeF   = (unsigned short*)(ws + off); off += (size_t)TC_ * B_ * E_ * 2;
  unsigned short* xeB   = (unsigned short*)(ws + off); off += (size_t)TC_ * B_ * E_ * 2;
  unsigned short* xpF   = (unsigned short*)(ws + off); off += (size_t)TC_ * B_ * G3 * 2;
  unsigned short* xpB   = (unsigned short*)(ws + off); off += (size_t)TC_ * B_ * G3 * 2;
  unsigned short* h1    = (unsigned short*)(ws + off); off += (size_t)S_ * B_ * 512 * 2;

  if (ws_size < off) {  // workspace too small: emit sentinel and bail
    k_sentinel<<<1, 1, 0, stream>>>(dout);
    return;
  }

  k_cvt<<<(2 * G3 * E_ + 255) / 256, 256, 0, stream>>>(Wih0, W0b, 2 * G3 * E_);
  k_cvt<<<(2 * G3 * H_ + 255) / 256, 256, 0, stream>>>(Whh0, Whh0b, 2 * G3 * H_);
  k_cvt<<<(G3 * 512 + 255) / 256, 256, 0, stream>>>(Wih1, W1b, G3 * 512);   // fwd dir only
  k_cvt<<<(G3 * H_ + 255) / 256, 256, 0, stream>>>(Whh1, Whh1b, G3 * H_);   // fwd dir only

  const int MCH = TC_ * B_;  // 8192 rows per chunk GEMM
  for (int c = 0; c < NCH; c++) {
    int s0 = c * TC_;
    k_embed_chunk<<<(2 * MCH * 32) / 256, 256, 0, stream>>>(coord, flag, pos, cW, femb,
                                                            xeF, xeB, s0);
    k_gemm_bt<<<(G3 / 128) * (MCH / 128), 256, 0, stream>>>(xeF, W0b, xpF, bih0,
                                                            MCH, G3, E_);
    k_gemm_bt<<<(G3 / 128) * (MCH / 128), 256, 0, stream>>>(xeB, W0b + (size_t)G3 * E_,
                                                            xpB, bih0 + G3, MCH, G3, E_);
    k_scan_chunk<<<16, 512, 0, stream>>>(xpF, xpB, Whh0b, bhh0, hstate0, h1, s0, 1);
  }
  for (int c = 0; c < NCH; c++) {
    int s0 = c * TC_;
    k_gemm_bt<<<(G3 / 128) * (MCH / 128), 256, 0, stream>>>(
        h1 + (size_t)s0 * B_ * 512, W1b, xpF, bih1, MCH, G3, 512);
    k_scan_chunk<<<8, 512, 0, stream>>>(xpF, xpF, Whh1b, bhh1, hstate1, nullptr, s0, 0);
  }
  k_final<<<B_, 256, 0, stream>>>(h1, hstate1, Wih1, bih1, bhh1, outW, outb, dout);
}